// Round 6
// baseline (1238.361 us; speedup 1.0000x reference)
//
#include <hip/hip_runtime.h>
#include <hip/hip_bf16.h>
#include <cstdint>

#define HD 64
#define NNODES 200000
#define NMSG 1800000

typedef short bf8 __attribute__((ext_vector_type(8)));
typedef float f32x4 __attribute__((ext_vector_type(4)));

// ---- order-preserving float <-> uint for atomicMax ----
__device__ __forceinline__ unsigned enc_f32(float f) {
    unsigned u = __float_as_uint(f);
    return (u & 0x80000000u) ? ~u : (u | 0x80000000u);
}
__device__ __forceinline__ float dec_f32(unsigned v) {
    return (v & 0x80000000u) ? __uint_as_float(v & 0x7fffffffu)
                             : __uint_as_float(~v);
}
__device__ __forceinline__ ushort f2bf(float f) {
    unsigned u = __float_as_uint(f);
    return (ushort)((u + 0x7fffu + ((u >> 16) & 1u)) >> 16);
}
__device__ __forceinline__ float bf2f(ushort b) {
    return __uint_as_float(((unsigned)b) << 16);
}
__device__ __forceinline__ void atom_pk(ushort* p, float lo, float hi) {
    __hip_bfloat162 v;
    v.x = __float2bfloat16(lo);
    v.y = __float2bfloat16(hi);
    (void)unsafeAtomicAdd((__hip_bfloat162*)p, v);
}

// ================= weight prep: fp32 -> bf16 frag-linear =====================
struct PrepArgs {
    const float* src[8];
    ushort*      dst[8];
    int din[8], dout[8], nelem[8];
};

__global__ __launch_bounds__(256) void prep_w(PrepArgs pa, int total) {
    int stride = gridDim.x * 256;
    for (int i = blockIdx.x * 256 + threadIdx.x; i < total; i += stride) {
        int e = i;
        #pragma unroll
        for (int m = 0; m < 8; m++) {
            if (e < pa.nelem[m]) {
                int din = pa.din[m], dout = pa.dout[m];
                int n = e / din, k = e - n * din;
                pa.dst[m][(k >> 5) * dout * 32 + n * 32 + (k & 31)] = f2bf(pa.src[m][e]);
                e = 0x7fffffff;
            } else e -= pa.nelem[m];
        }
    }
}

// ================= CSR build (int atomics only) =============================
__device__ __forceinline__ int msg_node(int g, const int* i0, const int* i1,
                                        const int* i2) {
    return (g < 600000) ? i0[g] : (g < 1200000) ? i1[g - 600000] : i2[g - 1200000];
}

__global__ __launch_bounds__(256) void count_kernel(
    const int* __restrict__ i0, const int* __restrict__ i1, const int* __restrict__ i2,
    int* __restrict__ cursor)
{
    int g = blockIdx.x * 256 + threadIdx.x;
    if (g < NMSG) atomicAdd(cursor + msg_node(g, i0, i1, i2), 1);
}

__global__ __launch_bounds__(1024) void scan_kernel(
    int* __restrict__ cursor, int* __restrict__ rowptr)
{
    __shared__ int sums[1024];
    const int t = threadIdx.x;
    const int CH = (NNODES + 1023) / 1024;
    int lo = t * CH, hi = min(lo + CH, NNODES);
    int s = 0;
    for (int i = lo; i < hi; i++) s += cursor[i];
    sums[t] = s;
    __syncthreads();
    for (int off = 1; off < 1024; off <<= 1) {
        int v = (t >= off) ? sums[t - off] : 0;
        __syncthreads();
        sums[t] += v;
        __syncthreads();
    }
    int running = (t == 0) ? 0 : sums[t - 1];
    for (int i = lo; i < hi; i++) {
        int c = cursor[i];
        rowptr[i] = running;
        cursor[i] = running;      // becomes the fill cursor
        running += c;
    }
    if (t == 1023) rowptr[NNODES] = running;
}

__global__ __launch_bounds__(256) void fill_perm(
    const int* __restrict__ i0, const int* __restrict__ i1, const int* __restrict__ i2,
    int* __restrict__ cursor, int* __restrict__ perm)
{
    int g = blockIdx.x * 256 + threadIdx.x;
    if (g >= NMSG) return;
    int pos = atomicAdd(cursor + msg_node(g, i0, i1, i2), 1);
    perm[pos] = g;
}

// ================= MFMA layer ==============================================
template<int DIN, int DOUT, int NT, int PDIN>
__device__ __forceinline__ void mfma_layer(
    const ushort* __restrict__ WT, const float* __restrict__ bias,
    const ushort* __restrict__ Xs, int wave, int lane, f32x4 acc[2][NT])
{
    constexpr int KS = DIN / 32;
    const int q = lane >> 4, ln = lane & 15, n0 = wave * NT * 16;
    bf8 bf[NT][KS];
    #pragma unroll
    for (int nt = 0; nt < NT; nt++)
        #pragma unroll
        for (int ks = 0; ks < KS; ks++)
            bf[nt][ks] = *(const bf8*)(WT + (size_t)ks * DOUT * 32
                                          + (n0 + nt * 16 + ln) * 32 + q * 8);
    #pragma unroll
    for (int nt = 0; nt < NT; nt++) {
        float bv = bias[n0 + nt * 16 + ln];
        acc[0][nt] = f32x4{bv, bv, bv, bv};
        acc[1][nt] = f32x4{bv, bv, bv, bv};
    }
    #pragma unroll
    for (int mt = 0; mt < 2; mt++) {
        bf8 af[KS];
        #pragma unroll
        for (int ks = 0; ks < KS; ks++)
            af[ks] = *(const bf8*)(Xs + (mt * 16 + ln) * PDIN + ks * 32 + q * 8);
        #pragma unroll
        for (int ks = 0; ks < KS; ks++)
            #pragma unroll
            for (int nt = 0; nt < NT; nt++)
                acc[mt][nt] = __builtin_amdgcn_mfma_f32_16x16x32_bf16(
                    af[ks], bf[nt][ks], acc[mt][nt], 0, 0, 0);
    }
}

// ---- gather 32 tuples x A rows from fp32 ns, converting to bf16 ------------
template<int A, int PD>
__device__ __forceinline__ void gather_tile(
    const float* __restrict__ ns, const int* __restrict__ idx,
    int t0, int tid, ushort* __restrict__ Xs)
{
    for (int lin = tid; lin < 32 * A * 8; lin += 256) {
        int slot = lin >> 3, part = lin & 7;
        int node = idx[t0 * A + slot];
        int row = slot / A, sub = slot - row * A;
        const float* src = ns + (size_t)node * HD + part * 8;
        float4 f0 = *(const float4*)src;
        float4 f1 = *(const float4*)(src + 4);
        ushort tmp[8] = { f2bf(f0.x), f2bf(f0.y), f2bf(f0.z), f2bf(f0.w),
                          f2bf(f1.x), f2bf(f1.y), f2bf(f1.z), f2bf(f1.w) };
        *(uint4*)(Xs + row * PD + sub * 64 + part * 8) = *(uint4*)tmp;
    }
}

// ================= PHASE PATH: rel kernel -> dense Msg ======================
template<int A>
__global__ __launch_bounds__(256) void rel_phase(
    const float* __restrict__ ns, const int* __restrict__ idx,
    const ushort* __restrict__ wt1, const float* __restrict__ b1,
    const ushort* __restrict__ wt2, const float* __restrict__ b2,
    ushort* __restrict__ Msg, int relbase, unsigned* __restrict__ Mword)
{
    constexpr int D  = A * HD;
    constexpr int PD = D + 8;
    constexpr int NT = D / 64;
    __shared__ __align__(16) ushort Xs[32 * PD];
    __shared__ __align__(16) ushort Hs[32 * PD];
    __shared__ float wred[4];

    const int tid = threadIdx.x;
    const int t0  = blockIdx.x * 32;
    const int wave = tid >> 6, lane = tid & 63;
    const int q = lane >> 4, ln = lane & 15, n0 = wave * NT * 16;

    gather_tile<A, PD>(ns, idx, t0, tid, Xs);
    __syncthreads();

    f32x4 acc[2][NT];
    mfma_layer<D, D, NT, PD>(wt1, b1, Xs, wave, lane, acc);
    #pragma unroll
    for (int mt = 0; mt < 2; mt++)
        #pragma unroll
        for (int nt = 0; nt < NT; nt++)
            #pragma unroll
            for (int r = 0; r < 4; r++)
                Hs[(mt * 16 + q * 4 + r) * PD + n0 + nt * 16 + ln] =
                    f2bf(fmaxf(acc[mt][nt][r], 0.f));
    __syncthreads();
    mfma_layer<D, D, NT, PD>(wt2, b2, Hs, wave, lane, acc);
    __syncthreads();   // all waves done reading Hs

    float m = -3.0e38f;
    #pragma unroll
    for (int mt = 0; mt < 2; mt++)
        #pragma unroll
        for (int nt = 0; nt < NT; nt++)
            #pragma unroll
            for (int r = 0; r < 4; r++) {
                float o = acc[mt][nt][r];
                m = fmaxf(m, o);
                Hs[(mt * 16 + q * 4 + r) * PD + n0 + nt * 16 + ln] = f2bf(o);
            }
    __syncthreads();

    // streaming copy Hs -> Msg (contiguous 32*A rows of 128B)
    const int gbase = relbase + t0 * A;
    for (int lin = tid; lin < 32 * A * 8; lin += 256) {
        int slot = lin >> 3, part = lin & 7;
        int row = slot / A, sub = slot - row * A;
        *(uint4*)(Msg + (size_t)(gbase + slot) * HD + part * 8) =
            *(uint4*)(Hs + row * PD + sub * 64 + part * 8);
    }

    #pragma unroll
    for (int off = 32; off; off >>= 1) m = fmaxf(m, __shfl_xor(m, off));
    if (lane == 0) wred[wave] = m;
    __syncthreads();
    if (tid == 0)
        atomicMax(Mword, enc_f32(fmaxf(fmaxf(wred[0], wred[1]),
                                       fmaxf(wred[2], wred[3]))));
}

// ====== PHASE PATH: fused CSR gather-reduce + LSE + update MLP ==============
__global__ __launch_bounds__(256) void reduce_update(
    const float* __restrict__ ns, const ushort* __restrict__ Msg,
    const int* __restrict__ rowptr, const int* __restrict__ perm,
    const unsigned* __restrict__ Mword,
    const ushort* __restrict__ wt1, const float* __restrict__ b1,
    const ushort* __restrict__ wt2, const float* __restrict__ b2,
    float* __restrict__ out)
{
    constexpr int D = 128, PD = D + 8;
    __shared__ __align__(16) ushort Xs[32 * PD];
    __shared__ __align__(16) ushort Hs[32 * PD];

    const int tid = threadIdx.x;
    const int r0  = blockIdx.x * 32;
    const float M = dec_f32(*Mword);

    const int grp = tid >> 3, sl = tid & 7;     // 8 threads per node
    const int n = r0 + grp;
    const int lo = rowptr[n], hi = rowptr[n + 1];

    float a8[8] = {0.f, 0.f, 0.f, 0.f, 0.f, 0.f, 0.f, 0.f};
    for (int e = lo; e < hi; e++) {
        int g = perm[e];
        uint4 v = *(const uint4*)(Msg + (size_t)g * HD + sl * 8);
        const ushort* pv = (const ushort*)&v;
        #pragma unroll
        for (int j = 0; j < 8; j++)
            a8[j] += __expf(8.f * (bf2f(pv[j]) - M));
    }
    ushort tmp[8];
    #pragma unroll
    for (int j = 0; j < 8; j++)
        tmp[j] = f2bf(0.125f * __logf(1e-16f + a8[j]) + M);
    *(uint4*)(Xs + grp * PD + sl * 8) = *(uint4*)tmp;
    {
        const float* src = ns + (size_t)n * HD + sl * 8;
        float4 f0 = *(const float4*)src;
        float4 f1 = *(const float4*)(src + 4);
        ushort t2[8] = { f2bf(f0.x), f2bf(f0.y), f2bf(f0.z), f2bf(f0.w),
                         f2bf(f1.x), f2bf(f1.y), f2bf(f1.z), f2bf(f1.w) };
        *(uint4*)(Xs + grp * PD + 64 + sl * 8) = *(uint4*)t2;
    }
    __syncthreads();

    const int wave = tid >> 6, lane = tid & 63;
    const int q = lane >> 4, ln = lane & 15;

    f32x4 acc[2][2];
    mfma_layer<128, 128, 2, PD>(wt1, b1, Xs, wave, lane, acc);
    #pragma unroll
    for (int mt = 0; mt < 2; mt++)
        #pragma unroll
        for (int nt = 0; nt < 2; nt++)
            #pragma unroll
            for (int r = 0; r < 4; r++)
                Hs[(mt * 16 + q * 4 + r) * PD + wave * 32 + nt * 16 + ln] =
                    f2bf(fmaxf(acc[mt][nt][r], 0.f));
    __syncthreads();

    f32x4 acc2[2][1];
    mfma_layer<128, 64, 1, PD>(wt2, b2, Hs, wave, lane, acc2);
    #pragma unroll
    for (int mt = 0; mt < 2; mt++)
        #pragma unroll
        for (int r = 0; r < 4; r++)
            out[(size_t)(r0 + mt * 16 + q * 4 + r) * HD + wave * 16 + ln] =
                acc2[mt][0][r];
}

// ================= FALLBACK PATH (proven R4 design, ~26 MB ws) ==============
template<int A>
__global__ __launch_bounds__(256) void rel_atomic(
    const float* __restrict__ ns, const int* __restrict__ idx,
    const ushort* __restrict__ wt1, const float* __restrict__ b1,
    const ushort* __restrict__ wt2, const float* __restrict__ b2,
    ushort* __restrict__ S16, unsigned* __restrict__ Mword)
{
    constexpr int D  = A * HD;
    constexpr int PD = D + 8;
    constexpr int NT = D / 64;
    __shared__ __align__(16) ushort Xs[32 * PD];
    __shared__ __align__(16) ushort Hs[32 * PD];
    __shared__ int Is[32 * A];
    __shared__ float wred[4];

    const int tid = threadIdx.x;
    const int t0  = blockIdx.x * 32;
    const int wave = tid >> 6, lane = tid & 63;
    const int q = lane >> 4, ln = lane & 15, n0 = wave * NT * 16;

    if (tid < 32 * A) Is[tid] = idx[t0 * A + tid];
    gather_tile<A, PD>(ns, idx, t0, tid, Xs);
    __syncthreads();

    f32x4 acc[2][NT];
    mfma_layer<D, D, NT, PD>(wt1, b1, Xs, wave, lane, acc);
    #pragma unroll
    for (int mt = 0; mt < 2; mt++)
        #pragma unroll
        for (int nt = 0; nt < NT; nt++)
            #pragma unroll
            for (int r = 0; r < 4; r++)
                Hs[(mt * 16 + q * 4 + r) * PD + n0 + nt * 16 + ln] =
                    f2bf(fmaxf(acc[mt][nt][r], 0.f));
    __syncthreads();
    mfma_layer<D, D, NT, PD>(wt2, b2, Hs, wave, lane, acc);

    float m = -3.0e38f;
    const bool even = (ln & 1) == 0;
    #pragma unroll
    for (int mt = 0; mt < 2; mt++)
        #pragma unroll
        for (int nt = 0; nt < NT; nt++) {
            int colg = n0 + nt * 16 + ln;
            int sub  = colg >> 6;
            int featp = (colg & 63) & ~1;
            float e[4], p[4];
            #pragma unroll
            for (int r = 0; r < 4; r++) {
                float o = acc[mt][nt][r];
                m = fmaxf(m, o);
                e[r] = __expf(8.f * o);
            }
            #pragma unroll
            for (int r = 0; r < 4; r++) p[r] = __shfl_xor(e[r], 1);
            #pragma unroll
            for (int j = 0; j < 2; j++) {
                int r   = even ? j : (2 + j);
                int row = mt * 16 + q * 4 + r;
                int node = Is[row * A + sub];
                float lov = even ? e[r] : p[r];
                float hiv = even ? p[r] : e[r];
                atom_pk(S16 + (size_t)node * HD + featp, lov, hiv);
            }
        }
    #pragma unroll
    for (int off = 32; off; off >>= 1) m = fmaxf(m, __shfl_xor(m, off));
    if (lane == 0) wred[wave] = m;
    __syncthreads();
    if (tid == 0)
        atomicMax(Mword, enc_f32(fmaxf(fmaxf(wred[0], wred[1]),
                                       fmaxf(wred[2], wred[3]))));
}

__global__ __launch_bounds__(256) void update_s16(
    const float* __restrict__ ns, const ushort* __restrict__ S16,
    const unsigned* __restrict__ Mword,
    const ushort* __restrict__ wt1, const float* __restrict__ b1,
    const ushort* __restrict__ wt2, const float* __restrict__ b2,
    float* __restrict__ out)
{
    constexpr int D = 128, PD = D + 8;
    __shared__ __align__(16) ushort Xs[32 * PD];
    __shared__ __align__(16) ushort Hs[32 * PD];

    const int tid = threadIdx.x;
    const int r0  = blockIdx.x * 32;
    const float corr = 1e-16f * __expf(8.f * dec_f32(*Mword));

    for (int lin = tid; lin < 32 * 16; lin += 256) {
        int row = lin >> 4, c8 = (lin & 15) * 8;
        if (c8 < 64) {
            ushort raw[8], tmp[8];
            *(uint4*)raw = *(const uint4*)(S16 + (size_t)(r0 + row) * HD + c8);
            #pragma unroll
            for (int j = 0; j < 8; j++)
                tmp[j] = f2bf(0.125f * __logf(bf2f(raw[j]) + corr));
            *(uint4*)(Xs + row * PD + c8) = *(uint4*)tmp;
        } else {
            const float* src = ns + (size_t)(r0 + row) * HD + (c8 - 64);
            float4 f0 = *(const float4*)src;
            float4 f1 = *(const float4*)(src + 4);
            ushort t2[8] = { f2bf(f0.x), f2bf(f0.y), f2bf(f0.z), f2bf(f0.w),
                             f2bf(f1.x), f2bf(f1.y), f2bf(f1.z), f2bf(f1.w) };
            *(uint4*)(Xs + row * PD + c8) = *(uint4*)t2;
        }
    }
    __syncthreads();

    const int wave = tid >> 6, lane = tid & 63;
    const int q = lane >> 4, ln = lane & 15;

    f32x4 acc[2][2];
    mfma_layer<128, 128, 2, PD>(wt1, b1, Xs, wave, lane, acc);
    #pragma unroll
    for (int mt = 0; mt < 2; mt++)
        #pragma unroll
        for (int nt = 0; nt < 2; nt++)
            #pragma unroll
            for (int r = 0; r < 4; r++)
                Hs[(mt * 16 + q * 4 + r) * PD + wave * 32 + nt * 16 + ln] =
                    f2bf(fmaxf(acc[mt][nt][r], 0.f));
    __syncthreads();

    f32x4 acc2[2][1];
    mfma_layer<128, 64, 1, PD>(wt2, b2, Hs, wave, lane, acc2);
    #pragma unroll
    for (int mt = 0; mt < 2; mt++)
        #pragma unroll
        for (int r = 0; r < 4; r++)
            out[(size_t)(r0 + mt * 16 + q * 4 + r) * HD + wave * 16 + ln] =
                acc2[mt][0][r];
}

// ================= host =====================================================
extern "C" void kernel_launch(void* const* d_in, const int* in_sizes, int n_in,
                              void* d_out, int out_size, void* d_ws, size_t ws_size,
                              hipStream_t stream)
{
    const float* ns   = (const float*)d_in[0];
    const int*   idx0 = (const int*)d_in[1];
    const int*   idx1 = (const int*)d_in[2];
    const int*   idx2 = (const int*)d_in[3];
    const float* W[8] = { (const float*)d_in[4],  (const float*)d_in[6],
                          (const float*)d_in[8],  (const float*)d_in[10],
                          (const float*)d_in[12], (const float*)d_in[14],
                          (const float*)d_in[16], (const float*)d_in[18] };
    const float* B[8] = { (const float*)d_in[5],  (const float*)d_in[7],
                          (const float*)d_in[9],  (const float*)d_in[11],
                          (const float*)d_in[13], (const float*)d_in[15],
                          (const float*)d_in[17], (const float*)d_in[19] };
    static const int DIN[8]  = {128,128,128,128,192,192,128,128};
    static const int DOUT[8] = {128,128,128,128,192,192,128, 64};

    const int T0 = in_sizes[1] / 2;   // 300000
    const int T1 = in_sizes[2] / 2;   // 300000
    const int T2 = in_sizes[3] / 3;   // 200000

    // ---- phase-path layout (exact byte offsets) ----
    const size_t oMsg    = 0;                       // 230,400,000
    const size_t oPerm   = 230400000;               //   7,200,000
    const size_t oRow    = 237600000;               //     800,064
    const size_t oCur    = 238400064;               //     800,000
    const size_t oMw     = 239200064;               //          64
    const size_t oWT     = 239200128;               //     327,680
    const size_t needPhase = 239527808;

    const bool phase = (ws_size >= needPhase);
    char* base = (char*)d_ws;

    ushort*   WTb;
    unsigned* Mw;
    if (phase) { WTb = (ushort*)(base + oWT); Mw = (unsigned*)(base + oMw); }
    else       { WTb = (ushort*)(base + 25600064); Mw = (unsigned*)(base + 25600000); }

    PrepArgs pa;
    int total = 0;
    ushort* wt[8];
    {
        ushort* p = WTb;
        for (int m = 0; m < 8; m++) {
            pa.src[m] = W[m];
            pa.dst[m] = p;  wt[m] = p;
            pa.din[m] = DIN[m]; pa.dout[m] = DOUT[m];
            pa.nelem[m] = DIN[m] * DOUT[m];
            p += pa.nelem[m];
            total += pa.nelem[m];
        }
    }
    prep_w<<<640, 256, 0, stream>>>(pa, total);

    if (phase) {
        ushort* Msg    = (ushort*)(base + oMsg);
        int*    perm   = (int*)(base + oPerm);
        int*    rowptr = (int*)(base + oRow);
        int*    cursor = (int*)(base + oCur);

        hipMemsetAsync(cursor, 0, 800064, stream);            // cursor + Mw
        count_kernel<<<(NMSG + 255) / 256, 256, 0, stream>>>(idx0, idx1, idx2, cursor);
        scan_kernel<<<1, 1024, 0, stream>>>(cursor, rowptr);
        fill_perm<<<(NMSG + 255) / 256, 256, 0, stream>>>(idx0, idx1, idx2, cursor, perm);

        rel_phase<2><<<T0 / 32, 256, 0, stream>>>(ns, idx0, wt[0], B[0], wt[1], B[1],
                                                  Msg, 0, Mw);
        rel_phase<2><<<T1 / 32, 256, 0, stream>>>(ns, idx1, wt[2], B[2], wt[3], B[3],
                                                  Msg, 600000, Mw);
        rel_phase<3><<<T2 / 32, 256, 0, stream>>>(ns, idx2, wt[4], B[4], wt[5], B[5],
                                                  Msg, 1200000, Mw);
        reduce_update<<<NNODES / 32, 256, 0, stream>>>(ns, Msg, rowptr, perm, Mw,
                                                       wt[6], B[6], wt[7], B[7],
                                                       (float*)d_out);
    } else {
        ushort* S16 = (ushort*)base;
        hipMemsetAsync(S16, 0, 25600064, stream);             // S16 + Mw
        rel_atomic<2><<<T0 / 32, 256, 0, stream>>>(ns, idx0, wt[0], B[0], wt[1], B[1],
                                                   S16, Mw);
        rel_atomic<2><<<T1 / 32, 256, 0, stream>>>(ns, idx1, wt[2], B[2], wt[3], B[3],
                                                   S16, Mw);
        rel_atomic<3><<<T2 / 32, 256, 0, stream>>>(ns, idx2, wt[4], B[4], wt[5], B[5],
                                                   S16, Mw);
        update_s16<<<NNODES / 32, 256, 0, stream>>>(ns, S16, Mw, wt[6], B[6],
                                                    wt[7], B[7], (float*)d_out);
    }
}